// Round 19
// baseline (51.080 us; speedup 1.0000x reference)
//
#include <hip/hip_runtime.h>
#include <math.h>

#define N_ 4096
#define D_ 64
#define NC_ 1000
#define KQ_ 8192
#define VCOLS 9192          // NC + KQ real columns
#define VPAD  9216          // 72*128 padded
#define PCH   5             // 4 gemm col-group partials + 1 sup chunk
#define TEMP_INV 20.0f
#define M0 20.25f           // fixed softmax reference for gemm chunks (dots <= 1)
#define LOG2E 1.4426950408889634f
#define K2L  (TEMP_INV * LOG2E)
#define M0L  (M0 * LOG2E)

// workspace layout (float offsets)
#define WS_F     0
#define WS_CENT  (WS_F + N_*D_)
#define WS_SUPM  (WS_CENT + NC_*D_)
#define WS_PSUP  (WS_SUPM + N_)
#define WS_PCENT (WS_PSUP + N_)
#define WS_CEPN  (WS_PCENT + N_)     // 512 CE numerator partials
#define WS_CEPD  (WS_CEPN + 512)     // 512 CE denominator partials
#define WS_CSP   (WS_CEPD + 512)     // 16 contrast partials
#define WS_GS    (WS_CSP + 16)       // 128 gram dist-sum partials
#define WS_GM    (WS_GS + 128)       // 128 gram dist-min partials
#define WS_VF    (WS_GM + 128)       // 64 blocks x 64 dims: sum f
#define WS_VC    (WS_VF + 4096)      // 64 blocks x 64 dims: sum cent[label]
#define WS_TP    (WS_VC + 4096)      // 64: sum f.cent[label] partials
#define WS_CTR   (WS_TP + 64)        // completion counter (uint)
#define WS_PS    (WS_CTR + 4)        // N*PCH chunk sums
#define WS_BBF   (WS_PS + N_*PCH)    // ushort[VPAD*64]

#define K1_BLOCKS 2058               // prep
#define K2_BLOCKS 960                // 256 gemm + 512 sup + 128 gram + 64 stats
#define K3_BLOCKS 16

typedef __attribute__((ext_vector_type(8))) short short8_t;
typedef __attribute__((ext_vector_type(4))) float f32x4;

__device__ __forceinline__ ushort f2bf(float x) {
    union { float f; unsigned u; } v; v.f = x;
    unsigned r = (v.u + 0x7FFFu + ((v.u >> 16) & 1u)) >> 16;
    return (ushort)r;
}

// XOR-swizzle for [row][64-ushort] LDS tiles (row stride 128 B)
__device__ __forceinline__ int swz(int byte) {
    return byte ^ (((byte >> 7) & 7) << 4);
}

// async global->LDS, 16B per lane; lds base must be wave-uniform
__device__ __forceinline__ void gload16(const void* g, void* lds) {
    __builtin_amdgcn_global_load_lds(
        (const __attribute__((address_space(1))) unsigned int*)g,
        (__attribute__((address_space(3))) unsigned int*)lds, 16, 0, 0);
}

// K1: prep only
__global__ __launch_bounds__(256) void k1(const float* __restrict__ feats,
                                          const float* __restrict__ C,
                                          const float* __restrict__ queue,
                                          float* __restrict__ ws,
                                          ushort* __restrict__ B) {
    int b = blockIdx.x;
    int t = threadIdx.x;
    if (b == 0 && t == 0) ((unsigned*)ws)[WS_CTR] = 0u;
    if (b < 1024) {
        int row  = b * 4 + (t >> 6);
        int lane = t & 63;
        float x = feats[row * D_ + lane];
        float ss = x * x;
        #pragma unroll
        for (int m = 32; m >= 1; m >>= 1) ss += __shfl_xor(ss, m, 64);
        float y = x / fmaxf(sqrtf(ss), 1e-12f);
        ws[WS_F + row * D_ + lane] = y;
        B[(size_t)(NC_ + row) * D_ + lane] = f2bf(y);
    } else if (b < 1028) {
        int c = (b - 1024) * 256 + t;
        if (c >= NC_) return;
        float v[D_];
        float ss = 0.0f;
        #pragma unroll
        for (int d = 0; d < D_; ++d) { float x = C[d * NC_ + c]; v[d] = x; ss += x * x; }
        float inv = 1.0f / fmaxf(sqrtf(ss), 1e-12f);
        #pragma unroll
        for (int d = 0; d < D_; ++d) {
            float y = v[d] * inv;
            ws[WS_CENT + c * D_ + d] = y;
            B[(size_t)c * D_ + d] = f2bf(y);
        }
    } else {
        int q = (b - 1028) * 256 + t;             // over (4096+24)*64
        if (q >= (KQ_ - N_ + 24) * D_) return;
        int r = q >> 6, d = q & 63;
        ushort o = 0;
        if (r < KQ_ - N_) o = f2bf(queue[(size_t)(N_ + r) * D_ + d]);
        B[(size_t)(NC_ + N_ + r) * D_ + d] = o;
    }
}

// K2: gemm (0..255, 64 rows x 2304 cols, 3-buffer counted-vmcnt pipeline,
//     NO VMEM ops in the loop except the staging loads)
//     + sup CE (256..767, 2 rows/wave) + gram (768..895) + stats (896..959).
__global__ __launch_bounds__(256) void k2(const ushort* __restrict__ B,
                                          const float* __restrict__ logits,
                                          const int* __restrict__ labels,
                                          const float* __restrict__ log_prior,
                                          const float* __restrict__ class_weight,
                                          const float* __restrict__ f,
                                          const float* __restrict__ cent,
                                          float* __restrict__ ws) {
    __shared__ char smem[49664];
    int t = threadIdx.x;
    int l = t & 63, w = t >> 6;
    int bid = blockIdx.x;
    int wm = w >> 1, wn = w & 1;
    int lr = l & 15, lg = l >> 4;
    int lk = lg * 8;

    if (bid < 256) {
        // ------- pipelined gemm strip (3 buffers, counted vmcnt waits) ------
        char* bufA = smem;                       // 16 KB
        char* bufB = smem + 16384;               // 16 KB
        char* bufC = smem + 32768;               // 16 KB
        float (*ssum)[2] = (float(*)[2])(smem + 49152);

        int bx = bid & 63, cg = bid >> 6;        // 64 row tiles x 4 col groups
        int r0 = bx * 64;
        int cbase = cg * 2304;

        // stage A (8 KB) into bufC; A-frags read before tile 2 re-stages it
        const char* Ag = (const char*)(B + (size_t)(NC_ + r0) * D_);
        #pragma unroll
        for (int j = 0; j < 2; ++j) {
            int seg = w * 2 + j;
            int o = seg * 64 + l;
            int sc = o ^ ((o >> 3) & 7);
            gload16(Ag + sc * 16, bufC + seg * 1024);
        }
        __syncthreads();
        short8_t a[2][2];
        #pragma unroll
        for (int rf = 0; rf < 2; ++rf) {
            int row = wm * 32 + rf * 16 + lr;
            #pragma unroll
            for (int ks = 0; ks < 2; ++ks)
                a[rf][ks] = *(const short8_t*)(bufC + swz(row * 128 + ks * 64 + lg * 16));
        }
        __syncthreads();   // all waves have A-frags before bufC is restaged

        int lab[2][4];
        #pragma unroll
        for (int rf = 0; rf < 2; ++rf)
            #pragma unroll
            for (int reg = 0; reg < 4; ++reg)
                lab[rf][reg] = labels[r0 + wm * 32 + rf * 16 + lg * 4 + reg];

        const char* Bg = (const char*)(B + (size_t)cbase * D_);
        auto stageB = [&](int tile, char* buf) {
            const char* Bt = Bg + (size_t)tile * 16384;
            #pragma unroll
            for (int j = 0; j < 4; ++j) {
                int seg = w * 4 + j;
                int o = seg * 64 + l;
                int sc = o ^ ((o >> 3) & 7);
                gload16(Bt + sc * 16, buf + seg * 1024);
            }
        };

        float se[2][4] = {};
        float pc[2][4] = {};
        int   hit[2][4] = {};

        // prologue: tiles 0,1 in flight; wait tile 0 only (8 outstanding -> 4)
        stageB(0, bufA);
        stageB(1, bufB);
        asm volatile("s_waitcnt vmcnt(4)" ::: "memory");
        __builtin_amdgcn_s_barrier();
        __builtin_amdgcn_sched_barrier(0);

        // one pipeline step; loop VMEM ops = staging loads ONLY
        auto step = [&](char* cur, char* nxt, int it) {
            if (it < 16) stageB(it + 2, nxt);

            short8_t bfr[4][2];
            #pragma unroll
            for (int cf = 0; cf < 4; ++cf) {
                int col = wn * 64 + cf * 16 + lr;
                #pragma unroll
                for (int ks = 0; ks < 2; ++ks)
                    bfr[cf][ks] = *(const short8_t*)(cur + swz(col * 128 + ks * 64 + lg * 16));
            }

            f32x4 acc[2][4] = {};
            #pragma unroll
            for (int ks = 0; ks < 2; ++ks)
                #pragma unroll
                for (int rf = 0; rf < 2; ++rf)
                    #pragma unroll
                    for (int cf = 0; cf < 4; ++cf)
                        acc[rf][cf] = __builtin_amdgcn_mfma_f32_16x16x32_bf16(
                            a[rf][ks], bfr[cf][ks], acc[rf][cf], 0, 0, 0);

            // positive-center: register-accumulated (pure VALU, no stores)
            #pragma unroll
            for (int rf = 0; rf < 2; ++rf)
                #pragma unroll
                for (int reg = 0; reg < 4; ++reg) {
                    #pragma unroll
                    for (int cf = 0; cf < 4; ++cf) {
                        int gcol = cbase + it * 128 + wn * 64 + cf * 16 + lr;
                        bool m = (gcol == lab[rf][reg]);
                        pc[rf][reg]  = m ? acc[rf][cf][reg] : pc[rf][reg];
                        hit[rf][reg] = m ? 1 : hit[rf][reg];
                    }
                }

            #pragma unroll
            for (int rf = 0; rf < 2; ++rf)
                #pragma unroll
                for (int cf = 0; cf < 4; ++cf)
                    #pragma unroll
                    for (int reg = 0; reg < 4; ++reg)
                        se[rf][reg] += __builtin_amdgcn_exp2f(
                            fmaf(acc[rf][cf][reg], K2L, -M0L));

            // counted wait: tile it+1 landed; tile it+2 stays in flight
            if (it < 16) {
                asm volatile("s_waitcnt vmcnt(4)" ::: "memory");
            } else {
                asm volatile("s_waitcnt vmcnt(0)" ::: "memory");
            }
            __builtin_amdgcn_s_barrier();
            __builtin_amdgcn_sched_barrier(0);
        };

        for (int ms = 0; ms < 6; ++ms) {
            step(bufA, bufC, ms * 3 + 0);
            step(bufB, bufA, ms * 3 + 1);
            step(bufC, bufB, ms * 3 + 2);
        }

        // deferred positive-center stores (one per row, owning lane only)
        #pragma unroll
        for (int rf = 0; rf < 2; ++rf)
            #pragma unroll
            for (int reg = 0; reg < 4; ++reg)
                if (hit[rf][reg])
                    ws[WS_PCENT + r0 + wm * 32 + rf * 16 + lg * 4 + reg] = pc[rf][reg];

        // epilogue: one 16-lane reduce per row value, one partial per row
        #pragma unroll
        for (int rf = 0; rf < 2; ++rf)
            #pragma unroll
            for (int reg = 0; reg < 4; ++reg) {
                float v = se[rf][reg];
                #pragma unroll
                for (int msk = 1; msk < 16; msk <<= 1)
                    v += __shfl_xor(v, msk, 64);
                if (lr == 0) ssum[wm * 32 + rf * 16 + lg * 4 + reg][wn] = v;
            }
        __syncthreads();
        if (t < 64)
            ws[WS_PS + (size_t)(r0 + t) * PCH + cg] = ssum[t][0] + ssum[t][1];
    } else if (bid < 768) {
        // ---------------- sup CE: 2 rows per wave ----------------
        float* lp = (float*)smem;               // 1000 floats
        float (*cep)[2] = (float(*)[2])(smem + 4096);
        int sid = bid - 256;                    // 0..511
        if (t < 250) ((float4*)lp)[t] = ((const float4*)log_prior)[t];
        __syncthreads();
        float cen_acc = 0.0f, ced_acc = 0.0f;
        int rbase = sid * 8 + w * 2;
        #pragma unroll
        for (int rr = 0; rr < 2; ++rr) {
            int row = rbase + rr;
            const float* lrow = logits + (size_t)row * NC_;
            const float4* lrow4 = (const float4*)lrow;
            float vals[16];
            float m = -1e30f;
            #pragma unroll
            for (int it = 0; it < 4; ++it) {
                int idx = it * 64 + l;
                float4 v4 = (idx < 250) ? lrow4[idx]
                                        : make_float4(-1e30f, -1e30f, -1e30f, -1e30f);
                float4 p4 = (idx < 250) ? ((const float4*)lp)[idx]
                                        : make_float4(0, 0, 0, 0);
                vals[it * 4 + 0] = v4.x + p4.x;
                vals[it * 4 + 1] = v4.y + p4.y;
                vals[it * 4 + 2] = v4.z + p4.z;
                vals[it * 4 + 3] = v4.w + p4.w;
                #pragma unroll
                for (int k = 0; k < 4; ++k) m = fmaxf(m, vals[it * 4 + k]);
            }
            #pragma unroll
            for (int msk = 1; msk < 64; msk <<= 1) m = fmaxf(m, __shfl_xor(m, msk, 64));
            float s1 = 0.0f, s20 = 0.0f;
            #pragma unroll
            for (int k = 0; k < 16; ++k) {
                float d = vals[k] - m;
                s1  += __builtin_amdgcn_exp2f(d * LOG2E);
                s20 += __builtin_amdgcn_exp2f(d * K2L);
            }
            #pragma unroll
            for (int msk = 1; msk < 64; msk <<= 1) {
                s1  += __shfl_xor(s1, msk, 64);
                s20 += __shfl_xor(s20, msk, 64);
            }
            if (l == 0) {
                int lab = labels[row];
                float vpos = lrow[lab] + lp[lab];
                float wt = class_weight[lab];
                cen_acc += wt * (m + __logf(s1) - vpos);
                ced_acc += wt;
                ws[WS_SUPM + row] = TEMP_INV * m;
                ws[WS_PS + (size_t)row * PCH + (PCH - 1)] = s20;
                ws[WS_PSUP + row] = TEMP_INV * vpos;
            }
        }
        if (l == 0) { cep[w][0] = cen_acc; cep[w][1] = ced_acc; }
        __syncthreads();
        if (t == 0) {
            ws[WS_CEPN + sid] = cep[0][0] + cep[1][0] + cep[2][0] + cep[3][0];
            ws[WS_CEPD + sid] = cep[0][1] + cep[1][1] + cep[2][1] + cep[3][1];
        }
    } else if (bid < 896) {
        // ---------------- gram via MFMA (direct frags) ----------------
        float* gs4 = (float*)smem;
        float* gm4 = gs4 + 4;
        int g = bid - 768;             // 0..127
        int gr = g >> 3, gc = g & 7;
        int r0 = gr * 64 + wm * 32;
        int c0 = gc * 128 + wn * 64;

        const ushort* Af = B + (size_t)(r0 + lr) * D_ + lk;
        const ushort* Bf = B + (size_t)(c0 + lr) * D_ + lk;

        short8_t a[2][2], bfr[4][2];
        #pragma unroll
        for (int rf = 0; rf < 2; ++rf)
            #pragma unroll
            for (int ks = 0; ks < 2; ++ks)
                a[rf][ks] = *(const short8_t*)(Af + rf * 16 * D_ + ks * 32);
        #pragma unroll
        for (int cf = 0; cf < 4; ++cf)
            #pragma unroll
            for (int ks = 0; ks < 2; ++ks)
                bfr[cf][ks] = *(const short8_t*)(Bf + cf * 16 * D_ + ks * 32);

        f32x4 acc[2][4] = {};
        #pragma unroll
        for (int ks = 0; ks < 2; ++ks)
            #pragma unroll
            for (int rf = 0; rf < 2; ++rf)
                #pragma unroll
                for (int cf = 0; cf < 4; ++cf)
                    acc[rf][cf] = __builtin_amdgcn_mfma_f32_16x16x32_bf16(
                        a[rf][ks], bfr[cf][ks], acc[rf][cf], 0, 0, 0);

        float lsum = 0.0f, lmin = 1e30f;
        #pragma unroll
        for (int rf = 0; rf < 2; ++rf)
            #pragma unroll
            for (int cf = 0; cf < 4; ++cf)
                #pragma unroll
                for (int reg = 0; reg < 4; ++reg) {
                    int gi = r0 + rf * 16 + lg * 4 + reg;
                    int gj = c0 + cf * 16 + lr;
                    if (gi < NC_ && gj < NC_ && gi != gj) {
                        float d = sqrtf(fmaxf(2.0f - 2.0f * acc[rf][cf][reg], 1e-12f));
                        lsum += d;
                        lmin = fminf(lmin, d);
                    }
                }
        #pragma unroll
        for (int msk = 1; msk < 64; msk <<= 1) {
            lsum += __shfl_xor(lsum, msk, 64);
            lmin = fminf(lmin, __shfl_xor(lmin, msk, 64));
        }
        if (l == 0) { gs4[w] = lsum; gm4[w] = lmin; }
        __syncthreads();
        if (t == 0) {
            ws[WS_GS + g] = gs4[0] + gs4[1] + gs4[2] + gs4[3];
            ws[WS_GM + g] = fminf(fminf(gm4[0], gm4[1]), fminf(gm4[2], gm4[3]));
        }
    } else {
        // ---------------- stats partials ----------------
        float* svf = (float*)smem;             // [4][64]
        float* svc = svf + 256;
        float* stp = svc + 256;
        int sb = bid - 896;            // 0..63
        int wid = sb * 4 + w;          // 0..255
        float vf = 0.0f, vc = 0.0f, tacc = 0.0f;
        for (int i = wid; i < N_; i += 256) {
            float x = f[i * D_ + l];
            float c = cent[labels[i] * D_ + l];
            vf += x; vc += c; tacc += x * c;
        }
        #pragma unroll
        for (int msk = 32; msk >= 1; msk >>= 1) tacc += __shfl_xor(tacc, msk, 64);
        svf[w * 64 + l] = vf; svc[w * 64 + l] = vc;
        if (l == 0) stp[w] = tacc;
        __syncthreads();
        if (w == 0) {
            ws[WS_VF + sb * 64 + l] = svf[l] + svf[64 + l] + svf[128 + l] + svf[192 + l];
            ws[WS_VC + sb * 64 + l] = svc[l] + svc[64 + l] + svc[128 + l] + svc[192 + l];
            if (l == 0) ws[WS_TP + sb] = stp[0] + stp[1] + stp[2] + stp[3];
        }
    }
}

// K3: 16 blocks, lane-per-row contrast merge + last-block final combine
__global__ __launch_bounds__(256) void k3(float* __restrict__ ws,
                                          float* __restrict__ out) {
    int t = threadIdx.x;
    int w = t >> 6, l = t & 63;
    int bid = blockIdx.x;
    __shared__ unsigned done;
    __shared__ float cb[4];

    {
        int row = bid * 256 + t;
        const float* pv = ws + WS_PS + (size_t)row * PCH;
        float s = (pv[0] + pv[1]) + (pv[2] + pv[3]);
        float msup = ws[WS_SUPM + row];
        float ssup = pv[PCH - 1];
        float M = fmaxf(M0, msup);
        float stot = s * __builtin_amdgcn_exp2f((M0 - M) * LOG2E)
                   + ssup * __builtin_amdgcn_exp2f((msup - M) * LOG2E);
        float logS = __logf(stot + 1e-12f);
        float lp1 = ws[WS_PSUP + row] - M - logS;
        float lp2 = ws[WS_PCENT + row] * TEMP_INV - M - logS;
        float cacc = (lp1 + 0.02f * lp2) / (1.02f + 1e-12f);
        #pragma unroll
        for (int msk = 1; msk < 64; msk <<= 1) cacc += __shfl_xor(cacc, msk, 64);
        if (l == 0) cb[w] = cacc;
        __syncthreads();
        if (t == 0) ws[WS_CSP + bid] = cb[0] + cb[1] + cb[2] + cb[3];
    }

    __threadfence();
    if (t == 0) done = atomicAdd((unsigned*)ws + WS_CTR, 1u);
    __syncthreads();
    if (done != K3_BLOCKS - 1) return;
    __threadfence();

    float csum = (t < 16) ? ws[WS_CSP + t] : 0.0f;
    float cen = 0.0f, ced = 0.0f;
    #pragma unroll
    for (int k = 0; k < 2; ++k) {
        cen += ws[WS_CEPN + t + k * 256];
        ced += ws[WS_CEPD + t + k * 256];
    }
    float gsum = 0, gmin = 1e30f, vf = 0, vc = 0, tp = 0;
    if (t < 64) {
        tp = ws[WS_TP + t];
        #pragma unroll 8
        for (int b = 0; b < 64; ++b) {
            vf += ws[WS_VF + b * 64 + t];
            vc += ws[WS_VC + b * 64 + t];
        }
    }
    if (t < 128) { gsum = ws[WS_GS + t]; gmin = ws[WS_GM + t]; }
    float mu_d = vf * (1.0f / (float)N_);
    float vmu  = vc * mu_d;
    float mumu = mu_d * mu_d;
    #pragma unroll
    for (int m = 32; m >= 1; m >>= 1) {
        csum += __shfl_xor(csum, m, 64);
        cen  += __shfl_xor(cen, m, 64);
        ced  += __shfl_xor(ced, m, 64);
        gsum += __shfl_xor(gsum, m, 64);
        gmin = fminf(gmin, __shfl_xor(gmin, m, 64));
        vmu  += __shfl_xor(vmu, m, 64);
        mumu += __shfl_xor(mumu, m, 64);
        tp   += __shfl_xor(tp, m, 64);
    }
    __shared__ float red[4][8];
    if (l == 0) {
        red[w][0] = csum; red[w][1] = cen; red[w][2] = ced; red[w][3] = gsum;
        red[w][4] = gmin; red[w][5] = vmu; red[w][6] = mumu; red[w][7] = tp;
    }
    __syncthreads();
    if (t == 0) {
        float CSM = red[0][0] + red[1][0] + red[2][0] + red[3][0];
        float CEN = red[0][1] + red[1][1] + red[2][1] + red[3][1];
        float CED = red[0][2] + red[1][2] + red[2][2] + red[3][2];
        float GSM = red[0][3] + red[1][3] + red[2][3] + red[3][3];
        float GMN = fminf(fminf(red[0][4], red[1][4]), fminf(red[2][4], red[3][4]));
        float VMU = red[0][5] + red[1][5] + red[2][5] + red[3][5];
        float MUMU = red[0][6] + red[1][6] + red[2][6] + red[3][6];
        float T   = red[0][7] + red[1][7] + red[2][7] + red[3][7];
        float SW = 2.0f * (float)N_ - 2.0f * T;
        float SB = (float)N_ - 2.0f * VMU + (float)N_ * MUMU;
        float intra = SW / (float)N_;
        float fisher = SB / (SW + 1e-6f);
        float ce = CEN / CED;
        float contrast = -(CSM / (float)N_);
        float inter_mean = GSM / (float)(NC_ * (NC_ - 1));
        float reg = intra + 0.1f / (inter_mean + 1e-6f)
                  + 0.05f / (GMN + 1e-6f) + 0.1f / (fisher + 1e-6f);
        out[0] = ce + contrast + reg;
    }
}

extern "C" void kernel_launch(void* const* d_in, const int* in_sizes, int n_in,
                              void* d_out, int out_size, void* d_ws, size_t ws_size,
                              hipStream_t stream) {
    const float* feats        = (const float*)d_in[0];
    const float* logits       = (const float*)d_in[1];
    const int*   labels       = (const int*)d_in[2];
    const float* C            = (const float*)d_in[3];
    const float* queue        = (const float*)d_in[4];
    const float* log_prior    = (const float*)d_in[5];
    const float* class_weight = (const float*)d_in[6];
    float* ws  = (float*)d_ws;
    float* out = (float*)d_out;
    ushort* Bbf = (ushort*)(ws + WS_BBF);

    hipLaunchKernelGGL(k1, dim3(K1_BLOCKS), dim3(256), 0, stream,
                       feats, C, queue, ws, Bbf);
    hipLaunchKernelGGL(k2, dim3(K2_BLOCKS), dim3(256), 0, stream,
                       Bbf, logits, labels, log_prior, class_weight,
                       ws + WS_F, ws + WS_CENT, ws);
    hipLaunchKernelGGL(k3, dim3(K3_BLOCKS), dim3(256), 0, stream, ws, out);
}

// Round 20
// 39.923 us; speedup vs baseline: 1.2795x; 1.2795x over previous
//
#include <hip/hip_runtime.h>
#include <math.h>

#define N_ 4096
#define D_ 64
#define NC_ 1000
#define KQ_ 8192
#define VCOLS 9192          // NC + KQ real columns
#define VPAD  9216          // 72*128 padded
#define PCH   5             // 4 gemm col-group partials + 1 sup chunk
#define TEMP_INV 20.0f
#define M0 20.25f           // fixed softmax reference for gemm chunks (dots <= 1)
#define LOG2E 1.4426950408889634f
#define K2L  (TEMP_INV * LOG2E)
#define M0L  (M0 * LOG2E)

// workspace layout (float offsets)
#define WS_F     0
#define WS_CENT  (WS_F + N_*D_)
#define WS_SUPM  (WS_CENT + NC_*D_)
#define WS_PSUP  (WS_SUPM + N_)
#define WS_PCENT (WS_PSUP + N_)
#define WS_CEPN  (WS_PCENT + N_)     // 512 CE numerator partials
#define WS_CEPD  (WS_CEPN + 512)     // 512 CE denominator partials
#define WS_CSP   (WS_CEPD + 512)     // 16 contrast partials
#define WS_GS    (WS_CSP + 16)       // 128 gram dist-sum partials
#define WS_GM    (WS_GS + 128)       // 128 gram dist-min partials
#define WS_VF    (WS_GM + 128)       // 64 blocks x 64 dims: sum f
#define WS_VC    (WS_VF + 4096)      // 64 blocks x 64 dims: sum cent[label]
#define WS_TP    (WS_VC + 4096)      // 64: sum f.cent[label] partials
#define WS_CTR   (WS_TP + 64)        // completion counter (uint)
#define WS_PS    (WS_CTR + 4)        // N*PCH chunk sums
#define WS_BBF   (WS_PS + N_*PCH)    // ushort[VPAD*64]

#define K1_BLOCKS 2058               // prep
#define K2_BLOCKS 960                // 256 gemm + 512 sup + 128 gram + 64 stats
#define K3_BLOCKS 16

typedef __attribute__((ext_vector_type(8))) short short8_t;
typedef __attribute__((ext_vector_type(4))) float f32x4;

__device__ __forceinline__ ushort f2bf(float x) {
    union { float f; unsigned u; } v; v.f = x;
    unsigned r = (v.u + 0x7FFFu + ((v.u >> 16) & 1u)) >> 16;
    return (ushort)r;
}

// XOR-swizzle for [row][64-ushort] LDS tiles (row stride 128 B)
__device__ __forceinline__ int swz(int byte) {
    return byte ^ (((byte >> 7) & 7) << 4);
}

// async global->LDS, 16B per lane; lds base must be wave-uniform
__device__ __forceinline__ void gload16(const void* g, void* lds) {
    __builtin_amdgcn_global_load_lds(
        (const __attribute__((address_space(1))) unsigned int*)g,
        (__attribute__((address_space(3))) unsigned int*)lds, 16, 0, 0);
}

// K1: prep only
__global__ __launch_bounds__(256) void k1(const float* __restrict__ feats,
                                          const float* __restrict__ C,
                                          const float* __restrict__ queue,
                                          float* __restrict__ ws,
                                          ushort* __restrict__ B) {
    int b = blockIdx.x;
    int t = threadIdx.x;
    if (b == 0 && t == 0) ((unsigned*)ws)[WS_CTR] = 0u;
    if (b < 1024) {
        int row  = b * 4 + (t >> 6);
        int lane = t & 63;
        float x = feats[row * D_ + lane];
        float ss = x * x;
        #pragma unroll
        for (int m = 32; m >= 1; m >>= 1) ss += __shfl_xor(ss, m, 64);
        float y = x / fmaxf(sqrtf(ss), 1e-12f);
        ws[WS_F + row * D_ + lane] = y;
        B[(size_t)(NC_ + row) * D_ + lane] = f2bf(y);
    } else if (b < 1028) {
        int c = (b - 1024) * 256 + t;
        if (c >= NC_) return;
        float v[D_];
        float ss = 0.0f;
        #pragma unroll
        for (int d = 0; d < D_; ++d) { float x = C[d * NC_ + c]; v[d] = x; ss += x * x; }
        float inv = 1.0f / fmaxf(sqrtf(ss), 1e-12f);
        #pragma unroll
        for (int d = 0; d < D_; ++d) {
            float y = v[d] * inv;
            ws[WS_CENT + c * D_ + d] = y;
            B[(size_t)c * D_ + d] = f2bf(y);
        }
    } else {
        int q = (b - 1028) * 256 + t;             // over (4096+24)*64
        if (q >= (KQ_ - N_ + 24) * D_) return;
        int r = q >> 6, d = q & 63;
        ushort o = 0;
        if (r < KQ_ - N_) o = f2bf(queue[(size_t)(N_ + r) * D_ + d]);
        B[(size_t)(NC_ + N_ + r) * D_ + d] = o;
    }
}

// K2: gemm (0..255, dispatched first, 1/CU, long-running)
//     + sup CE (256..767, 2 rows/wave) + gram (768..895) + stats (896..959).
// gemm block: 64 rows x 2304 cols (18 tiles of 128 cols); A-frags in regs,
// B double-buffered via global_load_lds (pre-swizzled source), se in regs.
__global__ __launch_bounds__(256) void k2(const ushort* __restrict__ B,
                                          const float* __restrict__ logits,
                                          const int* __restrict__ labels,
                                          const float* __restrict__ log_prior,
                                          const float* __restrict__ class_weight,
                                          const float* __restrict__ f,
                                          const float* __restrict__ cent,
                                          float* __restrict__ ws) {
    __shared__ char smem[33280];
    int t = threadIdx.x;
    int l = t & 63, w = t >> 6;
    int bid = blockIdx.x;
    int wm = w >> 1, wn = w & 1;
    int lr = l & 15, lg = l >> 4;
    int lk = lg * 8;

    if (bid < 256) {
        // ---------------- pipelined gemm strip ----------------
        char* buf0 = smem;                       // 16 KB
        char* buf1 = smem + 16384;               // 16 KB
        float (*ssum)[2] = (float(*)[2])(smem + 32768);

        int bx = bid & 63, cg = bid >> 6;        // 64 row tiles x 4 col groups
        int r0 = bx * 64;
        int cbase = cg * 2304;

        // stage A (8 KB) into buf0: pre-swizzled source, linear LDS dest
        const char* Ag = (const char*)(B + (size_t)(NC_ + r0) * D_);
        #pragma unroll
        for (int j = 0; j < 2; ++j) {
            int seg = w * 2 + j;
            int o = seg * 64 + l;
            int sc = o ^ ((o >> 3) & 7);
            gload16(Ag + sc * 16, buf0 + seg * 1024);
        }
        __syncthreads();
        short8_t a[2][2];
        #pragma unroll
        for (int rf = 0; rf < 2; ++rf) {
            int row = wm * 32 + rf * 16 + lr;
            #pragma unroll
            for (int ks = 0; ks < 2; ++ks)
                a[rf][ks] = *(const short8_t*)(buf0 + swz(row * 128 + ks * 64 + lg * 16));
        }
        __syncthreads();

        int lab[2][4];
        if (cg == 0) {
            #pragma unroll
            for (int rf = 0; rf < 2; ++rf)
                #pragma unroll
                for (int reg = 0; reg < 4; ++reg)
                    lab[rf][reg] = labels[r0 + wm * 32 + rf * 16 + lg * 4 + reg];
        }

        const char* Bg = (const char*)(B + (size_t)cbase * D_);
        auto stageB = [&](int tile, char* buf) {
            const char* Bt = Bg + (size_t)tile * 16384;
            #pragma unroll
            for (int j = 0; j < 4; ++j) {
                int seg = w * 4 + j;
                int o = seg * 64 + l;
                int sc = o ^ ((o >> 3) & 7);
                gload16(Bt + sc * 16, buf + seg * 1024);
            }
        };

        stageB(0, buf0);
        __syncthreads();

        float se[2][4] = {};
        #pragma unroll 2
        for (int it = 0; it < 18; ++it) {
            char* cur = (it & 1) ? buf1 : buf0;
            char* nxt = (it & 1) ? buf0 : buf1;
            if (it < 17) stageB(it + 1, nxt);   // async, drains at barrier below

            short8_t bfr[4][2];
            #pragma unroll
            for (int cf = 0; cf < 4; ++cf) {
                int col = wn * 64 + cf * 16 + lr;
                #pragma unroll
                for (int ks = 0; ks < 2; ++ks)
                    bfr[cf][ks] = *(const short8_t*)(cur + swz(col * 128 + ks * 64 + lg * 16));
            }

            f32x4 acc[2][4] = {};
            #pragma unroll
            for (int ks = 0; ks < 2; ++ks)
                #pragma unroll
                for (int rf = 0; rf < 2; ++rf)
                    #pragma unroll
                    for (int cf = 0; cf < 4; ++cf)
                        acc[rf][cf] = __builtin_amdgcn_mfma_f32_16x16x32_bf16(
                            a[rf][ks], bfr[cf][ks], acc[rf][cf], 0, 0, 0);

            if (cg == 0 && it < 8) {
                #pragma unroll
                for (int rf = 0; rf < 2; ++rf)
                    #pragma unroll
                    for (int reg = 0; reg < 4; ++reg) {
                        #pragma unroll
                        for (int cf = 0; cf < 4; ++cf) {
                            int col = it * 128 + wn * 64 + cf * 16 + lr;
                            if (col == lab[rf][reg])
                                ws[WS_PCENT + r0 + wm * 32 + rf * 16 + lg * 4 + reg] =
                                    acc[rf][cf][reg];
                        }
                    }
            }

            #pragma unroll
            for (int rf = 0; rf < 2; ++rf)
                #pragma unroll
                for (int cf = 0; cf < 4; ++cf)
                    #pragma unroll
                    for (int reg = 0; reg < 4; ++reg)
                        se[rf][reg] += __builtin_amdgcn_exp2f(
                            fmaf(acc[rf][cf][reg], K2L, -M0L));

            __syncthreads();   // next tile staged + cur fully consumed
        }

        // epilogue: one 16-lane reduce per row value, one partial per row
        #pragma unroll
        for (int rf = 0; rf < 2; ++rf)
            #pragma unroll
            for (int reg = 0; reg < 4; ++reg) {
                float v = se[rf][reg];
                #pragma unroll
                for (int msk = 1; msk < 16; msk <<= 1)
                    v += __shfl_xor(v, msk, 64);
                if (lr == 0) ssum[wm * 32 + rf * 16 + lg * 4 + reg][wn] = v;
            }
        __syncthreads();
        if (t < 64)
            ws[WS_PS + (size_t)(r0 + t) * PCH + cg] = ssum[t][0] + ssum[t][1];
    } else if (bid < 768) {
        // ---------------- sup CE: 2 rows per wave ----------------
        float* lp = (float*)smem;               // 1000 floats
        float (*cep)[2] = (float(*)[2])(smem + 4096);
        int sid = bid - 256;                    // 0..511
        if (t < 250) ((float4*)lp)[t] = ((const float4*)log_prior)[t];
        __syncthreads();
        float cen_acc = 0.0f, ced_acc = 0.0f;
        int rbase = sid * 8 + w * 2;
        #pragma unroll
        for (int rr = 0; rr < 2; ++rr) {
            int row = rbase + rr;
            const float* lrow = logits + (size_t)row * NC_;
            const float4* lrow4 = (const float4*)lrow;
            float vals[16];
            float m = -1e30f;
            #pragma unroll
            for (int it = 0; it < 4; ++it) {
                int idx = it * 64 + l;
                float4 v4 = (idx < 250) ? lrow4[idx]
                                        : make_float4(-1e30f, -1e30f, -1e30f, -1e30f);
                float4 p4 = (idx < 250) ? ((const float4*)lp)[idx]
                                        : make_float4(0, 0, 0, 0);
                vals[it * 4 + 0] = v4.x + p4.x;
                vals[it * 4 + 1] = v4.y + p4.y;
                vals[it * 4 + 2] = v4.z + p4.z;
                vals[it * 4 + 3] = v4.w + p4.w;
                #pragma unroll
                for (int k = 0; k < 4; ++k) m = fmaxf(m, vals[it * 4 + k]);
            }
            #pragma unroll
            for (int msk = 1; msk < 64; msk <<= 1) m = fmaxf(m, __shfl_xor(m, msk, 64));
            float s1 = 0.0f, s20 = 0.0f;
            #pragma unroll
            for (int k = 0; k < 16; ++k) {
                float d = vals[k] - m;
                s1  += __builtin_amdgcn_exp2f(d * LOG2E);
                s20 += __builtin_amdgcn_exp2f(d * K2L);
            }
            #pragma unroll
            for (int msk = 1; msk < 64; msk <<= 1) {
                s1  += __shfl_xor(s1, msk, 64);
                s20 += __shfl_xor(s20, msk, 64);
            }
            if (l == 0) {
                int lab = labels[row];
                float vpos = lrow[lab] + lp[lab];
                float wt = class_weight[lab];
                cen_acc += wt * (m + __logf(s1) - vpos);
                ced_acc += wt;
                ws[WS_SUPM + row] = TEMP_INV * m;
                ws[WS_PS + (size_t)row * PCH + (PCH - 1)] = s20;
                ws[WS_PSUP + row] = TEMP_INV * vpos;
            }
        }
        if (l == 0) { cep[w][0] = cen_acc; cep[w][1] = ced_acc; }
        __syncthreads();
        if (t == 0) {
            ws[WS_CEPN + sid] = cep[0][0] + cep[1][0] + cep[2][0] + cep[3][0];
            ws[WS_CEPD + sid] = cep[0][1] + cep[1][1] + cep[2][1] + cep[3][1];
        }
    } else if (bid < 896) {
        // ---------------- gram via MFMA (direct frags) ----------------
        float* gs4 = (float*)smem;
        float* gm4 = gs4 + 4;
        int g = bid - 768;             // 0..127
        int gr = g >> 3, gc = g & 7;
        int r0 = gr * 64 + wm * 32;
        int c0 = gc * 128 + wn * 64;

        const ushort* Af = B + (size_t)(r0 + lr) * D_ + lk;
        const ushort* Bf = B + (size_t)(c0 + lr) * D_ + lk;

        short8_t a[2][2], bfr[4][2];
        #pragma unroll
        for (int rf = 0; rf < 2; ++rf)
            #pragma unroll
            for (int ks = 0; ks < 2; ++ks)
                a[rf][ks] = *(const short8_t*)(Af + rf * 16 * D_ + ks * 32);
        #pragma unroll
        for (int cf = 0; cf < 4; ++cf)
            #pragma unroll
            for (int ks = 0; ks < 2; ++ks)
                bfr[cf][ks] = *(const short8_t*)(Bf + cf * 16 * D_ + ks * 32);

        f32x4 acc[2][4] = {};
        #pragma unroll
        for (int ks = 0; ks < 2; ++ks)
            #pragma unroll
            for (int rf = 0; rf < 2; ++rf)
                #pragma unroll
                for (int cf = 0; cf < 4; ++cf)
                    acc[rf][cf] = __builtin_amdgcn_mfma_f32_16x16x32_bf16(
                        a[rf][ks], bfr[cf][ks], acc[rf][cf], 0, 0, 0);

        float lsum = 0.0f, lmin = 1e30f;
        #pragma unroll
        for (int rf = 0; rf < 2; ++rf)
            #pragma unroll
            for (int cf = 0; cf < 4; ++cf)
                #pragma unroll
                for (int reg = 0; reg < 4; ++reg) {
                    int gi = r0 + rf * 16 + lg * 4 + reg;
                    int gj = c0 + cf * 16 + lr;
                    if (gi < NC_ && gj < NC_ && gi != gj) {
                        float d = sqrtf(fmaxf(2.0f - 2.0f * acc[rf][cf][reg], 1e-12f));
                        lsum += d;
                        lmin = fminf(lmin, d);
                    }
                }
        #pragma unroll
        for (int msk = 1; msk < 64; msk <<= 1) {
            lsum += __shfl_xor(lsum, msk, 64);
            lmin = fminf(lmin, __shfl_xor(lmin, msk, 64));
        }
        if (l == 0) { gs4[w] = lsum; gm4[w] = lmin; }
        __syncthreads();
        if (t == 0) {
            ws[WS_GS + g] = gs4[0] + gs4[1] + gs4[2] + gs4[3];
            ws[WS_GM + g] = fminf(fminf(gm4[0], gm4[1]), fminf(gm4[2], gm4[3]));
        }
    } else {
        // ---------------- stats partials ----------------
        float* svf = (float*)smem;             // [4][64]
        float* svc = svf + 256;
        float* stp = svc + 256;
        int sb = bid - 896;            // 0..63
        int wid = sb * 4 + w;          // 0..255
        float vf = 0.0f, vc = 0.0f, tacc = 0.0f;
        for (int i = wid; i < N_; i += 256) {
            float x = f[i * D_ + l];
            float c = cent[labels[i] * D_ + l];
            vf += x; vc += c; tacc += x * c;
        }
        #pragma unroll
        for (int msk = 32; msk >= 1; msk >>= 1) tacc += __shfl_xor(tacc, msk, 64);
        svf[w * 64 + l] = vf; svc[w * 64 + l] = vc;
        if (l == 0) stp[w] = tacc;
        __syncthreads();
        if (w == 0) {
            ws[WS_VF + sb * 64 + l] = svf[l] + svf[64 + l] + svf[128 + l] + svf[192 + l];
            ws[WS_VC + sb * 64 + l] = svc[l] + svc[64 + l] + svc[128 + l] + svc[192 + l];
            if (l == 0) ws[WS_TP + sb] = stp[0] + stp[1] + stp[2] + stp[3];
        }
    }
}

// K3: 16 blocks, lane-per-row contrast merge + last-block final combine
__global__ __launch_bounds__(256) void k3(float* __restrict__ ws,
                                          float* __restrict__ out) {
    int t = threadIdx.x;
    int w = t >> 6, l = t & 63;
    int bid = blockIdx.x;
    __shared__ unsigned done;
    __shared__ float cb[4];

    {
        int row = bid * 256 + t;
        const float* pv = ws + WS_PS + (size_t)row * PCH;
        float s = (pv[0] + pv[1]) + (pv[2] + pv[3]);
        float msup = ws[WS_SUPM + row];
        float ssup = pv[PCH - 1];
        float M = fmaxf(M0, msup);
        float stot = s * __builtin_amdgcn_exp2f((M0 - M) * LOG2E)
                   + ssup * __builtin_amdgcn_exp2f((msup - M) * LOG2E);
        float logS = __logf(stot + 1e-12f);
        float lp1 = ws[WS_PSUP + row] - M - logS;
        float lp2 = ws[WS_PCENT + row] * TEMP_INV - M - logS;
        float cacc = (lp1 + 0.02f * lp2) / (1.02f + 1e-12f);
        #pragma unroll
        for (int msk = 1; msk < 64; msk <<= 1) cacc += __shfl_xor(cacc, msk, 64);
        if (l == 0) cb[w] = cacc;
        __syncthreads();
        if (t == 0) ws[WS_CSP + bid] = cb[0] + cb[1] + cb[2] + cb[3];
    }

    __threadfence();
    if (t == 0) done = atomicAdd((unsigned*)ws + WS_CTR, 1u);
    __syncthreads();
    if (done != K3_BLOCKS - 1) return;
    __threadfence();

    float csum = (t < 16) ? ws[WS_CSP + t] : 0.0f;
    float cen = 0.0f, ced = 0.0f;
    #pragma unroll
    for (int k = 0; k < 2; ++k) {
        cen += ws[WS_CEPN + t + k * 256];
        ced += ws[WS_CEPD + t + k * 256];
    }
    float gsum = 0, gmin = 1e30f, vf = 0, vc = 0, tp = 0;
    if (t < 64) {
        tp = ws[WS_TP + t];
        #pragma unroll 8
        for (int b = 0; b < 64; ++b) {
            vf += ws[WS_VF + b * 64 + t];
            vc += ws[WS_VC + b * 64 + t];
        }
    }
    if (t < 128) { gsum = ws[WS_GS + t]; gmin = ws[WS_GM + t]; }
    float mu_d = vf * (1.0f / (float)N_);
    float vmu  = vc * mu_d;
    float mumu = mu_d * mu_d;
    #pragma unroll
    for (int m = 32; m >= 1; m >>= 1) {
        csum += __shfl_xor(csum, m, 64);
        cen  += __shfl_xor(cen, m, 64);
        ced  += __shfl_xor(ced, m, 64);
        gsum += __shfl_xor(gsum, m, 64);
        gmin = fminf(gmin, __shfl_xor(gmin, m, 64));
        vmu  += __shfl_xor(vmu, m, 64);
        mumu += __shfl_xor(mumu, m, 64);
        tp   += __shfl_xor(tp, m, 64);
    }
    __shared__ float red[4][8];
    if (l == 0) {
        red[w][0] = csum; red[w][1] = cen; red[w][2] = ced; red[w][3] = gsum;
        red[w][4] = gmin; red[w][5] = vmu; red[w][6] = mumu; red[w][7] = tp;
    }
    __syncthreads();
    if (t == 0) {
        float CSM = red[0][0] + red[1][0] + red[2][0] + red[3][0];
        float CEN = red[0][1] + red[1][1] + red[2][1] + red[3][1];
        float CED = red[0][2] + red[1][2] + red[2][2] + red[3][2];
        float GSM = red[0][3] + red[1][3] + red[2][3] + red[3][3];
        float GMN = fminf(fminf(red[0][4], red[1][4]), fminf(red[2][4], red[3][4]));
        float VMU = red[0][5] + red[1][5] + red[2][5] + red[3][5];
        float MUMU = red[0][6] + red[1][6] + red[2][6] + red[3][6];
        float T   = red[0][7] + red[1][7] + red[2][7] + red[3][7];
        float SW = 2.0f * (float)N_ - 2.0f * T;
        float SB = (float)N_ - 2.0f * VMU + (float)N_ * MUMU;
        float intra = SW / (float)N_;
        float fisher = SB / (SW + 1e-6f);
        float ce = CEN / CED;
        float contrast = -(CSM / (float)N_);
        float inter_mean = GSM / (float)(NC_ * (NC_ - 1));
        float reg = intra + 0.1f / (inter_mean + 1e-6f)
                  + 0.05f / (GMN + 1e-6f) + 0.1f / (fisher + 1e-6f);
        out[0] = ce + contrast + reg;
    }
}

extern "C" void kernel_launch(void* const* d_in, const int* in_sizes, int n_in,
                              void* d_out, int out_size, void* d_ws, size_t ws_size,
                              hipStream_t stream) {
    const float* feats        = (const float*)d_in[0];
    const float* logits       = (const float*)d_in[1];
    const int*   labels       = (const int*)d_in[2];
    const float* C            = (const float*)d_in[3];
    const float* queue        = (const float*)d_in[4];
    const float* log_prior    = (const float*)d_in[5];
    const float* class_weight = (const float*)d_in[6];
    float* ws  = (float*)d_ws;
    float* out = (float*)d_out;
    ushort* Bbf = (ushort*)(ws + WS_BBF);

    hipLaunchKernelGGL(k1, dim3(K1_BLOCKS), dim3(256), 0, stream,
                       feats, C, queue, ws, Bbf);
    hipLaunchKernelGGL(k2, dim3(K2_BLOCKS), dim3(256), 0, stream,
                       Bbf, logits, labels, log_prior, class_weight,
                       ws + WS_F, ws + WS_CENT, ws);
    hipLaunchKernelGGL(k3, dim3(K3_BLOCKS), dim3(256), 0, stream, ws, out);
}